// Round 2
// baseline (16529.175 us; speedup 1.0000x reference)
//
#include <hip/hip_runtime.h>

typedef _Float16 f16;
typedef _Float16 f16x8 __attribute__((ext_vector_type(8)));
typedef float f32x4 __attribute__((ext_vector_type(4)));

#define STEPS 512
#define BATCHN 256
#define HID 1024
#define EMBN 100
#define KTOT 1152
#define XPAD 128
#define NBLK 512

__device__ __forceinline__ float sigm(float x){ return 1.f/(1.f+__expf(-x)); }
__device__ __forceinline__ float tanh_f(float x){
    float e = __expf(2.f*fabsf(x));
    float r = 1.f - 2.f/(e+1.f);
    return x >= 0.f ? r : -r;
}
// select {a0,a1,a2,a3}[idx] without runtime-indexed array (rule #20)
__device__ __forceinline__ float pick4(float a0, float a1, float a2, float a3, int idx){
    float t0 = (idx & 1) ? a1 : a0;
    float t1 = (idx & 1) ? a3 : a2;
    return (idx & 2) ? t1 : t0;
}

// Pack W_h (1024 rows) + W_x (100 rows) + zero pad -> WT[4096][1152] fp16 hi/lo.
// Column J = cg*32 + n*16 + g*4 + um  (cg 0..127, n 0..1, gate g 0..3, um 0..3)
// -> unit u = cg*8 + n*4 + um. Also bias[J].
__global__ void pack_w(const float* __restrict__ Whi_, const float* __restrict__ Whf_,
                       const float* __restrict__ Who_, const float* __restrict__ Whc_,
                       const float* __restrict__ Wxi_, const float* __restrict__ Wxf_,
                       const float* __restrict__ Wxo_, const float* __restrict__ Wxc_,
                       const float* __restrict__ bi_, const float* __restrict__ bf_,
                       const float* __restrict__ bo_, const float* __restrict__ bc_,
                       f16* __restrict__ WThi, f16* __restrict__ WTlo, float* __restrict__ biasP)
{
    int J = blockIdx.x;                 // 0..4095
    int cg = J >> 5, n = (J >> 4) & 1, g = (J >> 2) & 3, um = J & 3;
    int u = cg*8 + n*4 + um;
    const float* Wh = (g==0)?Whi_:(g==1)?Whf_:(g==2)?Who_:Whc_;
    const float* Wx = (g==0)?Wxi_:(g==1)?Wxf_:(g==2)?Wxo_:Wxc_;
    for (int k = threadIdx.x; k < KTOT; k += blockDim.x){
        float v = 0.f;
        if (k < 1024)       v = Wh[(size_t)k*HID + u];
        else if (k < 1124)  v = Wx[(size_t)(k-1024)*HID + u];
        f16 hi = (f16)v;
        WThi[(size_t)J*KTOT + k] = hi;
        WTlo[(size_t)J*KTOT + k] = (f16)(v - (float)hi);
    }
    if (threadIdx.x == 0){
        const float* bb = (g==0)?bi_:(g==1)?bf_:(g==2)?bo_:bc_;
        biasP[J] = bb[u];
    }
}

// X[t][row][0..127] = fp16(emb[tokens[row][t]][kx]) (zero padded 100..127)
__global__ void pack_x(const int* __restrict__ tokens, const float* __restrict__ emb,
                       f16* __restrict__ Xbuf)
{
    int bid = blockIdx.x;               // t*256 + row
    int t = bid >> 8, row = bid & 255;
    int tok = tokens[(size_t)row*STEPS + t];
    int kx = threadIdx.x;               // 0..127
    float v = (kx < EMBN) ? emb[(size_t)tok*EMBN + kx] : 0.f;
    Xbuf[(size_t)bid*XPAD + kx] = (f16)v;
}

__global__ void pack_h0(const float* __restrict__ H0, f16* __restrict__ Hb)
{
    int i = blockIdx.x*blockDim.x + threadIdx.x;
    if (i < BATCHN*HID) Hb[i] = (f16)H0[i];
}

// Persistent LSTM: 512 blocks (4 batch-groups x 128 col-groups) x 256 threads,
// 2 blocks/CU. Weights in VGPRs (hi/lo fp16, 144 regs), C in registers,
// H ping-pongs fp16 in global, flag-array grid barrier per step.
__global__ __launch_bounds__(256, 2) void lstm_main(
    const f16* __restrict__ WThi, const f16* __restrict__ WTlo,
    const f16* __restrict__ Xbuf, const float* __restrict__ biasP,
    const float* __restrict__ C0, f16* __restrict__ Ha, f16* __restrict__ Hb,
    const float* __restrict__ dw, const float* __restrict__ db,
    float* __restrict__ out, unsigned int* __restrict__ flags)
{
    const int bid = blockIdx.x;
    const int bg = bid & 3, cg = bid >> 2;      // cg 0..127
    const int tid = threadIdx.x;
    const int w = tid >> 6, l = tid & 63, lr = l & 15, lhi = l >> 4;

    __shared__ f32x4 red[4][4][2][64];          // [owner_rt][giver_wave][n][lane], 32KB
    __shared__ int s_bail;
    if (tid == 0) s_bail = 0;

    // ---- persistent B fragments: 9 k-tiles x {hi,lo} x 2 col-tiles = 144 VGPRs ----
    f16x8 Bf[9][2][2];
    #pragma unroll
    for (int kt = 0; kt < 9; kt++){
        int k0 = (w*9 + kt)*32 + lhi*8;
        #pragma unroll
        for (int n = 0; n < 2; n++){
            size_t off = (size_t)(cg*32 + n*16 + lr)*KTOT + k0;
            Bf[kt][0][n] = *(const f16x8*)(WThi + off);
            Bf[kt][1][n] = *(const f16x8*)(WTlo + off);
        }
    }
    float bs[2][4];
    #pragma unroll
    for (int n = 0; n < 2; n++)
        #pragma unroll
        for (int g = 0; g < 4; g++)
            bs[n][g] = biasP[cg*32 + n*16 + g*4 + (l & 3)];

    const int rowbase = bg*64 + w*16 + lhi*4;   // kept rowtile = global rt w
    const int un0 = cg*8 + (l & 3);             // unit for n: un0 + n*4
    const int gs = lr >> 2;                     // this lane's gate index
    float Cr[2][4];
    #pragma unroll
    for (int n = 0; n < 2; n++)
        #pragma unroll
        for (int r = 0; r < 4; r++)
            Cr[n][r] = C0[(size_t)(rowbase + r)*HID + un0 + n*4];

    for (int t = 0; t < STEPS; t++){
        const f16* Hrd = (t & 1) ? Hb : Ha;
        f16*       Hwr = (t & 1) ? Ha : Hb;

        f32x4 acc[4][2];
        #pragma unroll
        for (int q = 0; q < 4; q++)
            #pragma unroll
            for (int n = 0; n < 2; n++) acc[q][n] = (f32x4){0.f,0.f,0.f,0.f};

        #pragma unroll
        for (int kt = 0; kt < 9; kt++){
            int k0 = (w*9 + kt)*32;
            f16x8 Af[4];
            if (k0 < 1024){
                const f16* base = Hrd + k0 + lhi*8;
                #pragma unroll
                for (int q = 0; q < 4; q++){
                    int rtg = (w + q) & 3;            // local q=0 -> global rt w
                    Af[q] = *(const f16x8*)(base + (size_t)(bg*64 + rtg*16 + lr)*HID);
                }
            } else {
                const f16* base = Xbuf + (size_t)t*BATCHN*XPAD + (k0 - 1024) + lhi*8;
                #pragma unroll
                for (int q = 0; q < 4; q++){
                    int rtg = (w + q) & 3;
                    Af[q] = *(const f16x8*)(base + (size_t)(bg*64 + rtg*16 + lr)*XPAD);
                }
            }
            #pragma unroll
            for (int q = 0; q < 4; q++)
                #pragma unroll
                for (int n = 0; n < 2; n++){
                    acc[q][n] = __builtin_amdgcn_mfma_f32_16x16x32_f16(Af[q], Bf[kt][0][n], acc[q][n], 0,0,0);
                    acc[q][n] = __builtin_amdgcn_mfma_f32_16x16x32_f16(Af[q], Bf[kt][1][n], acc[q][n], 0,0,0);
                }
        }

        // ---- cross-wave K reduction (give away local tiles q=1..3) ----
        #pragma unroll
        for (int q = 1; q < 4; q++){
            int owner = (w + q) & 3;
            #pragma unroll
            for (int n = 0; n < 2; n++) red[owner][w][n][l] = acc[q][n];
        }
        __syncthreads();
        #pragma unroll
        for (int q = 1; q < 4; q++){
            int giver = (w + q) & 3;
            #pragma unroll
            for (int n = 0; n < 2; n++) acc[0][n] += red[w][giver][n][l];
        }

        // ---- epilogue: gather 4 gates across lanes (xor 4/8/12), update C,H ----
        #pragma unroll
        for (int n = 0; n < 2; n++){
            #pragma unroll
            for (int r = 0; r < 4; r++){
                float a0 = acc[0][n][r];                  // gate gs      of unit un0+n*4
                float a1 = __shfl_xor(a0, 4, 64);         // gate gs^1
                float a2 = __shfl_xor(a0, 8, 64);         // gate gs^2
                float a3 = __shfl_xor(a0, 12, 64);        // gate gs^3
                float gi = pick4(a0,a1,a2,a3, gs    ) + bs[n][0];
                float gf = pick4(a0,a1,a2,a3, gs ^ 1) + bs[n][1];
                float go = pick4(a0,a1,a2,a3, gs ^ 2) + bs[n][2];
                float gc = pick4(a0,a1,a2,a3, gs ^ 3) + bs[n][3];
                float I = sigm(gi), F = sigm(gf), O = sigm(go), G = tanh_f(gc);
                float c = F*Cr[n][r] + I*G;
                Cr[n][r] = c;
                float h = O*tanh_f(c);
                if (gs == 0)
                    Hwr[(size_t)(rowbase + r)*HID + un0 + n*4] = (f16)h;
            }
        }

        // ---- grid barrier: per-block flag store + coalesced poll (no RMW) ----
        __syncthreads();
        if (w == 0){
            if (tid == 0){
                __builtin_amdgcn_fence(__ATOMIC_RELEASE, "agent");
                __hip_atomic_store(&flags[bid], (unsigned)(t+1), __ATOMIC_RELAXED, __HIP_MEMORY_SCOPE_AGENT);
            }
            unsigned tgt = (unsigned)(t+1), guard = 0;
            for (;;){
                bool ok = true;
                #pragma unroll
                for (int j = 0; j < 8; j++)
                    ok = ok && (__hip_atomic_load(&flags[l + 64*j], __ATOMIC_RELAXED, __HIP_MEMORY_SCOPE_AGENT) >= tgt);
                if (__all(ok)) break;
                if (++guard > 1000000u){ s_bail = 1; break; }
                __builtin_amdgcn_s_sleep(1);
            }
            if (tid == 0) __builtin_amdgcn_fence(__ATOMIC_ACQUIRE, "agent");
        }
        __syncthreads();
        if (s_bail) break;   // barrier failed: exit fast with wrong output, don't hang
    }

    // ---- final dense: H(final, in Ha) @ dense_w + dense_b -> out[256][2] ----
    if (cg == 0){
        const f16* Hf = Ha;                     // t=511 wrote Ha
        int rl = tid >> 2, j = (tid >> 1) & 1, half = tid & 1;
        int row = bg*64 + rl;
        const f16* hrow = Hf + (size_t)row*HID + half*512;
        float s = 0.f;
        for (int v = 0; v < 64; v++){
            f16x8 h8 = *(const f16x8*)(hrow + v*8);
            #pragma unroll
            for (int e = 0; e < 8; e++)
                s += (float)h8[e] * dw[(size_t)(half*512 + v*8 + e)*2 + j];
        }
        s += __shfl_xor(s, 1, 64);
        if (half == 0) out[(size_t)row*2 + j] = s + db[j];
    }
}

extern "C" void kernel_launch(void* const* d_in, const int* in_sizes, int n_in,
                              void* d_out, int out_size, void* d_ws, size_t ws_size,
                              hipStream_t stream)
{
    const int*   tokens = (const int*)d_in[0];
    const float* H0  = (const float*)d_in[1];
    const float* C0  = (const float*)d_in[2];
    const float* Wxi = (const float*)d_in[3];
    const float* Whi = (const float*)d_in[4];
    const float* bi  = (const float*)d_in[5];
    const float* Wxf = (const float*)d_in[6];
    const float* Whf = (const float*)d_in[7];
    const float* bf  = (const float*)d_in[8];
    const float* Wxo = (const float*)d_in[9];
    const float* Who = (const float*)d_in[10];
    const float* bo  = (const float*)d_in[11];
    const float* Wxc = (const float*)d_in[12];
    const float* Whc = (const float*)d_in[13];
    const float* bc  = (const float*)d_in[14];
    const float* emb = (const float*)d_in[15];
    const float* dw  = (const float*)d_in[16];
    const float* db  = (const float*)d_in[17];
    float* out = (float*)d_out;

    char* ws = (char*)d_ws;
    size_t off = 0;
    auto alloc = [&](size_t bytes){ void* p = ws + off; off += (bytes + 255) & ~(size_t)255; return p; };
    f16* WThi = (f16*)alloc((size_t)4096*KTOT*2);
    f16* WTlo = (f16*)alloc((size_t)4096*KTOT*2);
    f16* Xbuf = (f16*)alloc((size_t)STEPS*BATCHN*XPAD*2);
    f16* Ha   = (f16*)alloc((size_t)BATCHN*HID*2);
    f16* Hb   = (f16*)alloc((size_t)BATCHN*HID*2);
    float* biasP = (float*)alloc(4096*sizeof(float));
    unsigned int* flags = (unsigned int*)alloc(NBLK*sizeof(unsigned int));
    if (off > ws_size) return;   // workspace too small: fail loud

    hipMemsetAsync(flags, 0, NBLK*sizeof(unsigned int), stream);
    pack_w<<<4096, 256, 0, stream>>>(Whi,Whf,Who,Whc, Wxi,Wxf,Wxo,Wxc, bi,bf,bo,bc,
                                     WThi, WTlo, biasP);
    pack_x<<<STEPS*BATCHN, 128, 0, stream>>>(tokens, emb, Xbuf);
    pack_h0<<<(BATCHN*HID + 255)/256, 256, 0, stream>>>(H0, Ha);
    lstm_main<<<NBLK, 256, 0, stream>>>(WThi, WTlo, Xbuf, biasP, C0, Ha, Hb,
                                        dw, db, out, flags);
}

// Round 4
// 6974.078 us; speedup vs baseline: 2.3701x; 2.3701x over previous
//
#include <hip/hip_runtime.h>

typedef _Float16 f16;
typedef _Float16 f16x8 __attribute__((ext_vector_type(8)));
typedef float f32x4 __attribute__((ext_vector_type(4)));

#define STEPS 512
#define BATCHN 256
#define HID 1024
#define EMBN 100
#define KTOT 1152
#define XPAD 128
#define NBLK 256

__device__ __forceinline__ float sigm(float x){ return 1.f/(1.f+__expf(-x)); }
__device__ __forceinline__ float tanh_f(float x){
    float e = __expf(2.f*fabsf(x));
    float r = 1.f - 2.f/(e+1.f);
    return x >= 0.f ? r : -r;
}
// select {a0,a1,a2,a3}[idx] without runtime-indexed array (rule #20)
__device__ __forceinline__ float pick4(float a0, float a1, float a2, float a3, int idx){
    float t0 = (idx & 1) ? a1 : a0;
    float t1 = (idx & 1) ? a3 : a2;
    return (idx & 2) ? t1 : t0;
}

// Pack W_h(1024 rows)+W_x(100)+pad -> WT[4096][1152] f16 hi/lo.
// Col J = cg*64 + ct*16 + g*4 + um -> unit u = cg*16 + ct*4 + um. Also bias[J].
__global__ void pack_w(const float* __restrict__ Whi_, const float* __restrict__ Whf_,
                       const float* __restrict__ Who_, const float* __restrict__ Whc_,
                       const float* __restrict__ Wxi_, const float* __restrict__ Wxf_,
                       const float* __restrict__ Wxo_, const float* __restrict__ Wxc_,
                       const float* __restrict__ bi_, const float* __restrict__ bf_,
                       const float* __restrict__ bo_, const float* __restrict__ bc_,
                       f16* __restrict__ WThi, f16* __restrict__ WTlo, float* __restrict__ biasP)
{
    int J = blockIdx.x;                 // 0..4095
    int cg = J >> 6, ct = (J >> 4) & 3, g = (J >> 2) & 3, um = J & 3;
    int u = cg*16 + ct*4 + um;
    const float* Wh = (g==0)?Whi_:(g==1)?Whf_:(g==2)?Who_:Whc_;
    const float* Wx = (g==0)?Wxi_:(g==1)?Wxf_:(g==2)?Wxo_:Wxc_;
    for (int k = threadIdx.x; k < KTOT; k += blockDim.x){
        float v = 0.f;
        if (k < 1024)       v = Wh[(size_t)k*HID + u];
        else if (k < 1124)  v = Wx[(size_t)(k-1024)*HID + u];
        f16 hi = (f16)v;
        WThi[(size_t)J*KTOT + k] = hi;
        WTlo[(size_t)J*KTOT + k] = (f16)(v - (float)hi);
    }
    if (threadIdx.x == 0){
        const float* bb = (g==0)?bi_:(g==1)?bf_:(g==2)?bo_:bc_;
        biasP[J] = bb[u];
    }
}

__global__ void pack_x(const int* __restrict__ tokens, const float* __restrict__ emb,
                       f16* __restrict__ Xbuf)
{
    int bid = blockIdx.x;               // t*256 + row
    int t = bid >> 8, row = bid & 255;
    int tok = tokens[(size_t)row*STEPS + t];
    int kx = threadIdx.x;               // 0..127
    float v = (kx < EMBN) ? emb[(size_t)tok*EMBN + kx] : 0.f;
    Xbuf[(size_t)bid*XPAD + kx] = (f16)v;
}

__global__ void pack_h0(const float* __restrict__ H0, f16* __restrict__ Hb)
{
    int i = blockIdx.x*blockDim.x + threadIdx.x;
    if (i < BATCHN*HID) Hb[i] = (f16)H0[i];
}

// 3-deep pipelined A-tile load. H rows: device-scope (sc1, LLC). X rows: plain cached.
#define ISSUE(kt_, AF) do {                                                              \
    const int kb_ = w*288 + (kt_)*32;                                                    \
    if (kb_ < 1024) {                                                                    \
        const f16* hb_ = Hrd + kb_ + lhi*8;                                              \
        asm volatile("global_load_dwordx4 %0, %1, off sc1" : "=v"(AF[0]) : "v"(hb_ + (size_t)rA[0]*HID)); \
        asm volatile("global_load_dwordx4 %0, %1, off sc1" : "=v"(AF[1]) : "v"(hb_ + (size_t)rA[1]*HID)); \
        asm volatile("global_load_dwordx4 %0, %1, off sc1" : "=v"(AF[2]) : "v"(hb_ + (size_t)rA[2]*HID)); \
        asm volatile("global_load_dwordx4 %0, %1, off sc1" : "=v"(AF[3]) : "v"(hb_ + (size_t)rA[3]*HID)); \
    } else {                                                                             \
        const f16* xb_ = Xrow + (kb_ - 1024) + lhi*8;                                    \
        asm volatile("global_load_dwordx4 %0, %1, off" : "=v"(AF[0]) : "v"(xb_ + (size_t)rA[0]*XPAD)); \
        asm volatile("global_load_dwordx4 %0, %1, off" : "=v"(AF[1]) : "v"(xb_ + (size_t)rA[1]*XPAD)); \
        asm volatile("global_load_dwordx4 %0, %1, off" : "=v"(AF[2]) : "v"(xb_ + (size_t)rA[2]*XPAD)); \
        asm volatile("global_load_dwordx4 %0, %1, off" : "=v"(AF[3]) : "v"(xb_ + (size_t)rA[3]*XPAD)); \
    }                                                                                    \
} while(0)

#define WAITK(kt_) do {                                                                  \
    if ((kt_) < 7)       asm volatile("s_waitcnt vmcnt(8)" ::: "memory");                \
    else if ((kt_) == 7) asm volatile("s_waitcnt vmcnt(4)" ::: "memory");                \
    else                 asm volatile("s_waitcnt vmcnt(0)" ::: "memory");                \
    __builtin_amdgcn_sched_barrier(0);                                                   \
} while(0)

#define MM(kt_, AF) do {                                                                 \
    _Pragma("unroll")                                                                    \
    for (int q_ = 0; q_ < 4; q_++){                                                      \
        _Pragma("unroll")                                                                \
        for (int ct_ = 0; ct_ < 4; ct_++){                                               \
            acc[q_][ct_] = __builtin_amdgcn_mfma_f32_16x16x32_f16(AF[q_], Bf[kt_][0][ct_], acc[q_][ct_], 0,0,0); \
            acc[q_][ct_] = __builtin_amdgcn_mfma_f32_16x16x32_f16(AF[q_], Bf[kt_][1][ct_], acc[q_][ct_], 0,0,0); \
        }                                                                                \
    }                                                                                    \
} while(0)

// Persistent LSTM: 256 blocks (4 batch-groups x 64 col-groups) x 256 threads, 1/CU.
// Weights f16 hi/lo in VGPR+AGPR (288/lane). H + flags exchanged at device scope
// (sc1 -> LLC-coherent). No fences, no cache invalidation. Flag-array grid barrier.
__global__ __launch_bounds__(256, 1) void lstm_main(
    const f16* __restrict__ WThi, const f16* __restrict__ WTlo,
    const f16* __restrict__ Xbuf, const float* __restrict__ biasP,
    const float* __restrict__ C0, f16* __restrict__ Ha, f16* __restrict__ Hb,
    const float* __restrict__ dw, const float* __restrict__ db,
    float* __restrict__ out, unsigned* __restrict__ flags)
{
    __shared__ f32x4 red[4*3*4*64];     // [owner][q1][ct][lane], 48KB
    __shared__ int s_bail;

    const int bid = blockIdx.x;
    const int bg = bid & 3, cg = bid >> 2;
    const int tid = threadIdx.x;
    const int w = tid >> 6, l = tid & 63, lr = l & 15, lhi = l >> 4;
    const int um = l & 3, gs = lr >> 2;
    if (tid == 0) s_bail = 0;

    // ---- persistent weights: 9 kt x {hi,lo} x 4 ct = 288 VGPR/AGPR per lane ----
    f16x8 Bf[9][2][4];
    #pragma unroll
    for (int kt = 0; kt < 9; kt++){
        int k0 = w*288 + kt*32 + lhi*8;
        #pragma unroll
        for (int ct = 0; ct < 4; ct++){
            size_t off = (size_t)(cg*64 + ct*16 + lr)*KTOT + k0;
            Bf[kt][0][ct] = *(const f16x8*)(WThi + off);
            Bf[kt][1][ct] = *(const f16x8*)(WTlo + off);
        }
    }
    float bs[4][4];                      // [ct][gate]
    #pragma unroll
    for (int ct = 0; ct < 4; ct++)
        #pragma unroll
        for (int g = 0; g < 4; g++)
            bs[ct][g] = biasP[cg*64 + ct*16 + g*4 + um];

    int rA[4];
    #pragma unroll
    for (int q = 0; q < 4; q++) rA[q] = bg*64 + ((w + q) & 3)*16 + lr;
    const int myrow0 = bg*64 + w*16 + lhi*4;      // kept rowtile = global rt w
    const int colW = cg*16 + gs*4 + um;           // H-store column

    float Cr[4][4];                      // [ct][r], gs-redundant
    #pragma unroll
    for (int ct = 0; ct < 4; ct++)
        #pragma unroll
        for (int r = 0; r < 4; r++)
            Cr[ct][r] = C0[(size_t)(myrow0 + r)*HID + cg*16 + ct*4 + um];

    __syncthreads();

    for (int t = 0; t < STEPS; t++){
        const f16* Hrd = (t & 1) ? Hb : Ha;
        f16*       Hwr = (t & 1) ? Ha : Hb;
        const f16* Xrow = Xbuf + (size_t)t*BATCHN*XPAD;

        f32x4 acc[4][4];
        #pragma unroll
        for (int q = 0; q < 4; q++)
            #pragma unroll
            for (int ct = 0; ct < 4; ct++) acc[q][ct] = (f32x4){0.f,0.f,0.f,0.f};

        f16x8 Aa[4], Ab[4], Ac[4];
        ISSUE(0, Aa);
        ISSUE(1, Ab);
        #pragma unroll
        for (int kt = 0; kt < 9; kt++){
            if ((kt % 3) == 0){
                if (kt < 7) ISSUE(kt+2, Ac);
                WAITK(kt); MM(kt, Aa);
            } else if ((kt % 3) == 1){
                if (kt < 7) ISSUE(kt+2, Aa);
                WAITK(kt); MM(kt, Ab);
            } else {
                if (kt < 7) ISSUE(kt+2, Ab);
                WAITK(kt); MM(kt, Ac);
            }
        }

        // ---- cross-wave K reduction (kept tile q=0 <-> global rt w) ----
        #pragma unroll
        for (int q = 1; q < 4; q++){
            int o = (w + q) & 3;
            #pragma unroll
            for (int ct = 0; ct < 4; ct++)
                red[((o*3 + (q-1))*4 + ct)*64 + l] = acc[q][ct];
        }
        __syncthreads();
        #pragma unroll
        for (int q1 = 0; q1 < 3; q1++)
            #pragma unroll
            for (int ct = 0; ct < 4; ct++)
                acc[0][ct] += red[((w*3 + q1)*4 + ct)*64 + l];

        // ---- epilogue: gather gates (xor 4/8/12), update C, compute h ----
        float hall[4][4];
        #pragma unroll
        for (int ct = 0; ct < 4; ct++){
            #pragma unroll
            for (int r = 0; r < 4; r++){
                float a0 = acc[0][ct][r];
                float a1 = __shfl_xor(a0, 4, 64);
                float a2 = __shfl_xor(a0, 8, 64);
                float a3 = __shfl_xor(a0, 12, 64);
                float gi = pick4(a0,a1,a2,a3, gs    ) + bs[ct][0];
                float gf = pick4(a0,a1,a2,a3, gs ^ 1) + bs[ct][1];
                float go = pick4(a0,a1,a2,a3, gs ^ 2) + bs[ct][2];
                float gc = pick4(a0,a1,a2,a3, gs ^ 3) + bs[ct][3];
                float I = sigm(gi), F = sigm(gf), O = sigm(go), G = tanh_f(gc);
                float c = F*Cr[ct][r] + I*G;
                Cr[ct][r] = c;
                hall[ct][r] = O*tanh_f(c);
            }
        }

        // ---- H store: lane gs stores ct=gs -> each (unit,row) exactly once ----
        #pragma unroll
        for (int r = 0; r < 4; r++){
            float hv = pick4(hall[0][r], hall[1][r], hall[2][r], hall[3][r], gs);
            f16 h16 = (f16)hv;
            f16* p = Hwr + (size_t)(myrow0 + r)*HID + colW;
            __hip_atomic_store(p, h16, __ATOMIC_RELAXED, __HIP_MEMORY_SCOPE_AGENT);
        }
        asm volatile("s_waitcnt vmcnt(0)" ::: "memory");
        __syncthreads();

        // ---- grid barrier: per-block flag (device scope), coalesced poll ----
        if (tid == 0)
            __hip_atomic_store(&flags[bid], (unsigned)(t+1), __ATOMIC_RELAXED, __HIP_MEMORY_SCOPE_AGENT);
        if (w == 0){
            unsigned tgt = (unsigned)(t+1), guard = 0;
            for (;;){
                unsigned f0 = __hip_atomic_load(&flags[l      ], __ATOMIC_RELAXED, __HIP_MEMORY_SCOPE_AGENT);
                unsigned f1 = __hip_atomic_load(&flags[l +  64], __ATOMIC_RELAXED, __HIP_MEMORY_SCOPE_AGENT);
                unsigned f2 = __hip_atomic_load(&flags[l + 128], __ATOMIC_RELAXED, __HIP_MEMORY_SCOPE_AGENT);
                unsigned f3 = __hip_atomic_load(&flags[l + 192], __ATOMIC_RELAXED, __HIP_MEMORY_SCOPE_AGENT);
                bool ok = (f0 >= tgt) && (f1 >= tgt) && (f2 >= tgt) && (f3 >= tgt);
                if (__all(ok)) break;
                if (++guard > 2000000u){ s_bail = 1; break; }
                __builtin_amdgcn_s_sleep(1);
            }
        }
        __syncthreads();
        if (s_bail) break;
    }

    // ---- final dense: H(final, in Ha) @ dense_w + dense_b -> out[256][2] ----
    if (cg == 0 && !s_bail){
        int r = tid >> 2, j = (tid >> 1) & 1, half = tid & 1;
        int row = bg*64 + r;
        const f16* hrow = Ha + (size_t)row*HID + half*512;
        float s = 0.f;
        for (int v = 0; v < 64; v++){
            f16x8 h8;
            asm volatile("global_load_dwordx4 %0, %1, off sc1" : "=v"(h8) : "v"(hrow + v*8));
            asm volatile("s_waitcnt vmcnt(0)" ::: "memory");
            #pragma unroll
            for (int e = 0; e < 8; e++)
                s += (float)h8[e] * dw[(size_t)(half*512 + v*8 + e)*2 + j];
        }
        s += __shfl_xor(s, 1, 64);
        if (half == 0) out[(size_t)row*2 + j] = s + db[j];
    }
}

extern "C" void kernel_launch(void* const* d_in, const int* in_sizes, int n_in,
                              void* d_out, int out_size, void* d_ws, size_t ws_size,
                              hipStream_t stream)
{
    const int*   tokens = (const int*)d_in[0];
    const float* H0  = (const float*)d_in[1];
    const float* C0  = (const float*)d_in[2];
    const float* Wxi = (const float*)d_in[3];
    const float* Whi = (const float*)d_in[4];
    const float* bi  = (const float*)d_in[5];
    const float* Wxf = (const float*)d_in[6];
    const float* Whf = (const float*)d_in[7];
    const float* bf  = (const float*)d_in[8];
    const float* Wxo = (const float*)d_in[9];
    const float* Who = (const float*)d_in[10];
    const float* bo  = (const float*)d_in[11];
    const float* Wxc = (const float*)d_in[12];
    const float* Whc = (const float*)d_in[13];
    const float* bc  = (const float*)d_in[14];
    const float* emb = (const float*)d_in[15];
    const float* dw  = (const float*)d_in[16];
    const float* db  = (const float*)d_in[17];
    float* out = (float*)d_out;

    char* ws = (char*)d_ws;
    size_t off = 0;
    auto alloc = [&](size_t bytes){ void* p = ws + off; off += (bytes + 255) & ~(size_t)255; return p; };
    f16* WThi = (f16*)alloc((size_t)4096*KTOT*2);
    f16* WTlo = (f16*)alloc((size_t)4096*KTOT*2);
    f16* Xbuf = (f16*)alloc((size_t)STEPS*BATCHN*XPAD*2);
    f16* Ha   = (f16*)alloc((size_t)BATCHN*HID*2);
    f16* Hb   = (f16*)alloc((size_t)BATCHN*HID*2);
    float* biasP = (float*)alloc(4096*sizeof(float));
    unsigned* flags = (unsigned*)alloc(NBLK*sizeof(unsigned));
    if (off > ws_size) return;   // workspace too small: fail loud

    hipMemsetAsync(flags, 0, NBLK*sizeof(unsigned), stream);
    pack_w<<<4096, 256, 0, stream>>>(Whi,Whf,Who,Whc, Wxi,Wxf,Wxo,Wxc, bi,bf,bo,bc,
                                     WThi, WTlo, biasP);
    pack_x<<<STEPS*BATCHN, 128, 0, stream>>>(tokens, emb, Xbuf);
    pack_h0<<<(BATCHN*HID + 255)/256, 256, 0, stream>>>(H0, Ha);
    lstm_main<<<NBLK, 256, 0, stream>>>(WThi, WTlo, Xbuf, biasP, C0, Ha, Hb,
                                        dw, db, out, flags);
}